// Round 18
// baseline (507.139 us; speedup 1.0000x reference)
//
#include <hip/hip_runtime.h>
#include <hip/hip_fp16.h>
#include <cfloat>
#include <cstddef>

#define NODES 50000
#define EDGES 800000
#define HEADS 4
#define FEAT  64
#define HF    256   // HEADS*FEAT
#define NEG_SLOPE 0.2f

#define ROWS 32
#define PROJ_BLOCKS ((NODES + ROWS - 1) / ROWS)    // 1563
#define COUNT_BLOCKS ((EDGES + 511) / 512)         // 1563 (512-thread blocks)

// ============ CSR build ============

__global__ void zero_deg_kernel(int* __restrict__ deg) {
  int i = blockIdx.x * blockDim.x + threadIdx.x;
  if (i < NODES) deg[i] = 0;
}

// LDS-staged single-block scan: 4 chunks of 13312, coalesced I/O, 13 elems/thread.
#define SCHUNK 13312
#define SPER   13
__global__ __launch_bounds__(1024) void scan_kernel(const int* __restrict__ deg,
                                                    int* __restrict__ rowstart,
                                                    int* __restrict__ cursor) {
  __shared__ int buf[SCHUNK];          // 52 KB
  __shared__ int wsum[16];
  __shared__ int carry_s;
  const int tid = threadIdx.x, lane = tid & 63, wv = tid >> 6;
  if (tid == 0) carry_s = 0;
  for (int base = 0; base < NODES; base += SCHUNK) {
    const int sz = min(SCHUNK, NODES - base);
    for (int i = tid; i < sz; i += 1024) buf[i] = deg[base + i];
    __syncthreads();
    const int o = tid * SPER;
    int tsum = 0;
#pragma unroll
    for (int j = 0; j < SPER; ++j) {
      int idx = o + j;
      if (idx < sz) tsum += buf[idx];
    }
    int x = tsum;
#pragma unroll
    for (int off = 1; off < 64; off <<= 1) {
      int u = __shfl_up(x, off, 64);
      if (lane >= off) x += u;
    }
    if (lane == 63) wsum[wv] = x;
    __syncthreads();
    if (wv == 0) {
      int wval = (lane < 16) ? wsum[lane] : 0;
      int wx = wval;
#pragma unroll
      for (int off = 1; off < 16; off <<= 1) {
        int u = __shfl_up(wx, off, 64);
        if (lane >= off) wx += u;
      }
      if (lane < 16) wsum[lane] = wx - wval;   // exclusive wave offsets
    }
    __syncthreads();
    const int carry = carry_s;
    int run = carry + wsum[wv] + (x - tsum);   // thread's exclusive prefix
#pragma unroll
    for (int j = 0; j < SPER; ++j) {
      int idx = o + j;
      if (idx < sz) { int t = buf[idx]; buf[idx] = run; run += t; }
    }
    __syncthreads();
    for (int i = tid; i < sz; i += 1024) {
      int v = buf[i];
      rowstart[base + i] = v;
      cursor[base + i] = v;
    }
    __syncthreads();
    if (tid == 1023) carry_s = run;            // = carry + chunk total
    __syncthreads();
  }
}

__global__ void scatter_kernel(const int* __restrict__ src, const int* __restrict__ dst,
                               int* __restrict__ cursor, int* __restrict__ csr_src) {
  int e = blockIdx.x * blockDim.x + threadIdx.x;
  if (e < EDGES) {
    int pos = atomicAdd(&cursor[dst[e]], 1);
    csr_src[pos] = src[e];
  }
}

// ============ fused projection GEMM + attention logits (+optional edge count) ====
// Spill-proof K-split design (round-15 showed launch_bounds hint didn't un-spill
// the Wc[64]-per-thread version; non-node residual ~275us matches W re-read cost).
// 512 threads = 8 waves. Wave w covers columns c = w*32+(lane&31); lane>>5 picks
// the K-half. Each thread holds only Wc[32] (~50 VGPR total -> fits ANY allocator
// choice). K-halves combine via shfl_xor(32); el/er via in-wave butterfly + LDS
// per-wave partials + one block-level reduce at the end.
__device__ __forceinline__ void proj_body(
    const float* __restrict__ x, const float* __restrict__ W,
    const float* __restrict__ al, const float* __restrict__ ar,
    __half* __restrict__ h, float* __restrict__ el, float* __restrict__ er,
    int blk) {
  __shared__ float xs[ROWS * FEAT];        // 8 KB
  __shared__ float ehp[2][ROWS][8];        // 8 KB: el/er partial per (row, wave)
  const int tid = threadIdx.x;             // 0..511
  const int wv = tid >> 6;                 // 0..7
  const int lane = tid & 63;
  const int kh = lane >> 5;                // K-half 0/1
  const int c = wv * 32 + (lane & 31);     // output column 0..255
  const int head = c >> 6, f = c & 63;

  float Wc[32];
#pragma unroll
  for (int k = 0; k < 32; ++k) Wc[k] = W[(kh * 32 + k) * HF + c];
  const float alv = al[head * FEAT + f];
  const float arv = ar[head * FEAT + f];

  const int row0 = blk * ROWS;
  for (int i = tid; i < ROWS * FEAT; i += 512) {
    int r = row0 + (i >> 6);
    xs[i] = (r < NODES) ? x[(size_t)r * FEAT + (i & 63)] : 0.f;
  }
  __syncthreads();

  for (int r = 0; r < ROWS; ++r) {
    const int row = row0 + r;
    if (row >= NODES) break;
    const float4* xr = (const float4*)&xs[r * FEAT + kh * 32];
    float va = 0.f, vb = 0.f;
#pragma unroll
    for (int q = 0; q < 8; q += 2) {
      float4 a = xr[q], b = xr[q + 1];
      va += a.x * Wc[4 * q + 0] + a.y * Wc[4 * q + 1] +
            a.z * Wc[4 * q + 2] + a.w * Wc[4 * q + 3];
      vb += b.x * Wc[4 * q + 4] + b.y * Wc[4 * q + 5] +
            b.z * Wc[4 * q + 6] + b.w * Wc[4 * q + 7];
    }
    float v = va + vb;
    v += __shfl_xor(v, 32, 64);            // combine the two K-halves
    if (kh == 0) h[(size_t)row * HF + c] = __float2half(v);
    float sl = v * alv, sr = v * arv;
#pragma unroll
    for (int m = 1; m <= 16; m <<= 1) {    // butterfly over the 32 columns
      sl += __shfl_xor(sl, m, 64);
      sr += __shfl_xor(sr, m, 64);
    }
    if (lane == 0) { ehp[0][r][wv] = sl; ehp[1][r][wv] = sr; }
  }
  __syncthreads();
  // combine the two waves of each head -> el/er
  for (int i = tid; i < 2 * ROWS * HEADS; i += 512) {
    const int sel = (i >= ROWS * HEADS) ? 1 : 0;
    const int j = i - sel * ROWS * HEADS;   // row*HEADS + head
    const int r = j >> 2, hd = j & 3;
    const int row = row0 + r;
    if (row < NODES) {
      float s = ehp[sel][r][hd * 2 + 0] + ehp[sel][r][hd * 2 + 1];
      (sel ? er : el)[row * HEADS + hd] = s;
    }
  }
}

template<int WITH_COUNT>
__global__ __launch_bounds__(512, 2) void proj_kernel(
    const float* __restrict__ x, const float* __restrict__ W,
    const float* __restrict__ al, const float* __restrict__ ar,
    __half* __restrict__ h, float* __restrict__ el, float* __restrict__ er,
    const int* __restrict__ dst, int* __restrict__ deg) {
  if (WITH_COUNT && blockIdx.x >= PROJ_BLOCKS) {
    int e = (blockIdx.x - PROJ_BLOCKS) * 512 + threadIdx.x;
    if (e < EDGES) atomicAdd(&deg[dst[e]], 1);
    return;
  }
  proj_body(x, W, al, ar, h, el, er, blockIdx.x);
}

// ============ fused per-node: segment softmax + aggregation + bias/act/mean ====
__device__ __forceinline__ float lrelu(float s) { return s > 0.f ? s : NEG_SLOPE * s; }

__device__ __forceinline__ void gather_fma(const __half* __restrict__ h, int s,
                                           int hh, int fq, float av, float4& acc) {
  union { uint2 u; __half2 h2[2]; } cvt;
  cvt.u = *(const uint2*)(h + (size_t)s * HF + hh * FEAT + fq * 4);
  float2 f01 = __half22float2(cvt.h2[0]);
  float2 f23 = __half22float2(cvt.h2[1]);
  acc.x += f01.x * av;
  acc.y += f01.y * av;
  acc.z += f23.x * av;
  acc.w += f23.y * av;
}

template<int DO_TANH>
__global__ __launch_bounds__(256) void node_kernel(
    const int* __restrict__ rowstart, const int* __restrict__ deg,
    const int* __restrict__ csr_src,
    const float* __restrict__ el, const float* __restrict__ er,
    const __half* __restrict__ h, const float* __restrict__ bias,
    float* __restrict__ out) {
  const int node = (blockIdx.x * blockDim.x + threadIdx.x) >> 6;
  if (node >= NODES) return;
  const int lane = threadIdx.x & 63;
  const int hh = lane >> 4, fq = lane & 15;
  const int rs = rowstart[node];
  const int dg = deg[node];

  float4 acc = make_float4(0.f, 0.f, 0.f, 0.f);

  if (dg > 0) {
    const float4 erv = *(const float4*)&er[node * 4];
    if (dg <= 64) {
      // ---- fast path: one edge per lane; scores/alpha computed once ----
      int sL = 0;
      float s0 = -FLT_MAX, s1 = -FLT_MAX, s2 = -FLT_MAX, s3 = -FLT_MAX;
      if (lane < dg) {
        sL = csr_src[rs + lane];
        float4 ev = *(const float4*)&el[sL * 4];
        s0 = lrelu(ev.x + erv.x);
        s1 = lrelu(ev.y + erv.y);
        s2 = lrelu(ev.z + erv.z);
        s3 = lrelu(ev.w + erv.w);
      }
      float m0 = s0, m1 = s1, m2 = s2, m3 = s3;
#pragma unroll
      for (int off = 32; off; off >>= 1) {
        m0 = fmaxf(m0, __shfl_xor(m0, off, 64));
        m1 = fmaxf(m1, __shfl_xor(m1, off, 64));
        m2 = fmaxf(m2, __shfl_xor(m2, off, 64));
        m3 = fmaxf(m3, __shfl_xor(m3, off, 64));
      }
      float E0 = 0.f, E1 = 0.f, E2 = 0.f, E3 = 0.f;
      if (lane < dg) {
        E0 = __expf(s0 - m0);
        E1 = __expf(s1 - m1);
        E2 = __expf(s2 - m2);
        E3 = __expf(s3 - m3);
      }
      float q0 = E0, q1 = E1, q2 = E2, q3 = E3;
#pragma unroll
      for (int off = 32; off; off >>= 1) {
        q0 += __shfl_xor(q0, off, 64);
        q1 += __shfl_xor(q1, off, 64);
        q2 += __shfl_xor(q2, off, 64);
        q3 += __shfl_xor(q3, off, 64);
      }
      const float A0 = E0 / q0, A1 = E1 / q1, A2 = E2 / q2, A3 = E3 / q3;
      for (int i = 0; i < dg; ++i) {
        const int s = __shfl(sL, i, 64);
        const float a0 = __shfl(A0, i, 64);
        const float a1 = __shfl(A1, i, 64);
        const float a2 = __shfl(A2, i, 64);
        const float a3 = __shfl(A3, i, 64);
        const float av = (hh == 0) ? a0 : (hh == 1) ? a1 : (hh == 2) ? a2 : a3;
        gather_fma(h, s, hh, fq, av, acc);
      }
    } else {
      // ---- general 3-pass path (deg > 64; rare) ----
      float m0 = -FLT_MAX, m1 = -FLT_MAX, m2 = -FLT_MAX, m3 = -FLT_MAX;
      for (int i = lane; i < dg; i += 64) {
        int s = csr_src[rs + i];
        float4 ev = *(const float4*)&el[s * 4];
        m0 = fmaxf(m0, lrelu(ev.x + erv.x));
        m1 = fmaxf(m1, lrelu(ev.y + erv.y));
        m2 = fmaxf(m2, lrelu(ev.z + erv.z));
        m3 = fmaxf(m3, lrelu(ev.w + erv.w));
      }
#pragma unroll
      for (int off = 32; off; off >>= 1) {
        m0 = fmaxf(m0, __shfl_xor(m0, off, 64));
        m1 = fmaxf(m1, __shfl_xor(m1, off, 64));
        m2 = fmaxf(m2, __shfl_xor(m2, off, 64));
        m3 = fmaxf(m3, __shfl_xor(m3, off, 64));
      }
      float q0 = 0.f, q1 = 0.f, q2 = 0.f, q3 = 0.f;
      for (int i = lane; i < dg; i += 64) {
        int s = csr_src[rs + i];
        float4 ev = *(const float4*)&el[s * 4];
        q0 += __expf(lrelu(ev.x + erv.x) - m0);
        q1 += __expf(lrelu(ev.y + erv.y) - m1);
        q2 += __expf(lrelu(ev.z + erv.z) - m2);
        q3 += __expf(lrelu(ev.w + erv.w) - m3);
      }
#pragma unroll
      for (int off = 32; off; off >>= 1) {
        q0 += __shfl_xor(q0, off, 64);
        q1 += __shfl_xor(q1, off, 64);
        q2 += __shfl_xor(q2, off, 64);
        q3 += __shfl_xor(q3, off, 64);
      }
      const float r0 = 1.f / q0, r1 = 1.f / q1, r2 = 1.f / q2, r3 = 1.f / q3;
      for (int base = 0; base < dg; base += 64) {
        const int cnt = min(64, dg - base);
        int sL = 0;
        float A0 = 0.f, A1 = 0.f, A2 = 0.f, A3 = 0.f;
        if (base + lane < dg) {
          sL = csr_src[rs + base + lane];
          float4 ev = *(const float4*)&el[sL * 4];
          A0 = __expf(lrelu(ev.x + erv.x) - m0) * r0;
          A1 = __expf(lrelu(ev.y + erv.y) - m1) * r1;
          A2 = __expf(lrelu(ev.z + erv.z) - m2) * r2;
          A3 = __expf(lrelu(ev.w + erv.w) - m3) * r3;
        }
        for (int i = 0; i < cnt; ++i) {
          const int s = __shfl(sL, i, 64);
          const float a0 = __shfl(A0, i, 64);
          const float a1 = __shfl(A1, i, 64);
          const float a2 = __shfl(A2, i, 64);
          const float a3 = __shfl(A3, i, 64);
          const float av = (hh == 0) ? a0 : (hh == 1) ? a1 : (hh == 2) ? a2 : a3;
          gather_fma(h, s, hh, fq, av, acc);
        }
      }
    }
  }

  // ---- bias + activation + head-mean (cross-head shfl reduce) ----
  const float4 bv = *(const float4*)&bias[hh * FEAT + fq * 4];
  float vx = acc.x + bv.x, vy = acc.y + bv.y, vz = acc.z + bv.z, vw = acc.w + bv.w;
  if (DO_TANH) { vx = tanhf(vx); vy = tanhf(vy); vz = tanhf(vz); vw = tanhf(vw); }
#pragma unroll
  for (int off = 16; off <= 32; off <<= 1) {
    vx += __shfl_xor(vx, off, 64);
    vy += __shfl_xor(vy, off, 64);
    vz += __shfl_xor(vz, off, 64);
    vw += __shfl_xor(vw, off, 64);
  }
  if (hh == 0) {
    *(float4*)&out[(size_t)node * FEAT + fq * 4] =
        make_float4(vx * 0.25f, vy * 0.25f, vz * 0.25f, vw * 0.25f);
  }
}

// ============ launch ============

extern "C" void kernel_launch(void* const* d_in, const int* in_sizes, int n_in,
                              void* d_out, int out_size, void* d_ws, size_t ws_size,
                              hipStream_t stream) {
  const float* x   = (const float*)d_in[0];
  const int*   src = (const int*)d_in[1];
  const int*   dst = (const int*)d_in[2];
  const float* Ws[2]  = {(const float*)d_in[3], (const float*)d_in[7]};
  const float* als[2] = {(const float*)d_in[4], (const float*)d_in[8]};
  const float* ars[2] = {(const float*)d_in[5], (const float*)d_in[9]};
  const float* bs[2]  = {(const float*)d_in[6], (const float*)d_in[10]};

  float* ws = (float*)d_ws;
  const size_t NHF = (size_t)NODES * HF;   // 12.8M elems
  const size_t NF  = (size_t)NODES * FEAT; // 3.2M
  const size_t NH  = (size_t)NODES * HEADS;// 200K
  __half* hbuf = (__half*)ws;              // NHF halves = NHF/2 float slots
  float* x2   = ws + NHF / 2;
  float* el   = x2 + NF;
  float* er   = el + NH;
  int* ibase   = (int*)(er + NH);
  int* deg      = ibase;
  int* rowstart = ibase + NODES;
  int* cursor   = ibase + 2 * NODES;
  int* csr_src  = ibase + 3 * NODES;
  float* outp = (float*)d_out;

  const int edge_grid = (EDGES + 255) / 256;
  const int node_grid = (NODES * 64) / 256;  // one wave per node
  const int n_grid    = (NODES + 255) / 256;

  // zero degrees, then layer-1 projection fused with degree count
  zero_deg_kernel<<<n_grid, 256, 0, stream>>>(deg);
  proj_kernel<1><<<PROJ_BLOCKS + COUNT_BLOCKS, 512, 0, stream>>>(
      x, Ws[0], als[0], ars[0], hbuf, el, er, dst, deg);
  scan_kernel<<<1, 1024, 0, stream>>>(deg, rowstart, cursor);
  scatter_kernel<<<edge_grid, 256, 0, stream>>>(src, dst, cursor, csr_src);

  node_kernel<1><<<node_grid, 256, 0, stream>>>(rowstart, deg, csr_src, el, er,
                                                hbuf, bs[0], x2);
  proj_kernel<0><<<PROJ_BLOCKS, 512, 0, stream>>>(
      x2, Ws[1], als[1], ars[1], hbuf, el, er, dst, deg);
  node_kernel<0><<<node_grid, 256, 0, stream>>>(rowstart, deg, csr_src, el, er,
                                                hbuf, bs[1], outp);
}